// Round 2
// baseline (178270.288 us; speedup 1.0000x reference)
//
#include <hip/hip_runtime.h>

// NeuralODEDecoder on MI355X (gfx950).
//
// One persistent kernel, 128 WGs x 1024 threads (16 waves). Each WG owns a
// 16-row batch tile and runs the entire 990-step Euler integration +
// per-time decode (batch rows are independent).
//  - z state: fp32 in registers, in MFMA C/D fragment layout.
//  - activations: bf16 ping-pong LDS buffers, chunked [k/32][m][40] layout.
//  - weights: streamed from global (L2-resident) directly as B-fragments.
//
// DTYPE HEDGE (round 2): the harness's input dtype is ambiguous (bf16 label
// fired, but round-1 NaN is the signature of fp32-read-as-bf16). The t array
// discriminates on-device: word at byte offset 8 is 0x3F800000 (1.0f) for
// fp32 input, 0x40204000 (bf16 2.0,2.5) for bf16 input. Both paths compiled;
// grid-uniform branch; output dtype follows input dtype.
//
// mfma_f32_16x16x32_bf16: A[m=l&15][k=(l>>4)*8+j], B[n=l&15][k=(l>>4)*8+j],
// D: col=l&15, row=(l>>4)*4+reg (m89/m91-verified mapping).

typedef short short8 __attribute__((ext_vector_type(8)));
typedef float float4_ __attribute__((ext_vector_type(4)));

static constexpr int kB = 2048;
static constexpr int kT = 100;
static constexpr int kLatent = 256;
static constexpr int kHidden = 1024;
static constexpr int kOut = 512;
static constexpr int kSteps = 10;   // Euler substeps per interval
static constexpr int kRows = 16;    // batch rows per workgroup

// LDS activation layout: chunk k/32 is a [16][40] tile (80B row stride:
// 16B-aligned for ds_read_b128, <=2-way bank aliasing = free).
__device__ __forceinline__ int actIdx(int m, int k) {
  return ((k >> 5) * 640) + m * 40 + (k & 31);
}

__device__ __forceinline__ float bf2f(unsigned short s) {
  union { float f; unsigned u; } x;
  x.u = ((unsigned)s) << 16;
  return x.f;
}
__device__ __forceinline__ unsigned short f2bf(float f) {
  union { float f; unsigned u; } x;
  x.f = f;
  unsigned u = x.u;
  return (unsigned short)((u + 0x7fffu + ((u >> 16) & 1)) >> 16);  // RNE
}

template <typename T> struct Ld;
template <> struct Ld<unsigned short> {
  static __device__ __forceinline__ short8 ld8(const unsigned short* p) {
    return *(const short8*)p;
  }
  static __device__ __forceinline__ float ld1(const unsigned short* p) {
    return bf2f(*p);
  }
};
template <> struct Ld<float> {
  static __device__ __forceinline__ short8 ld8(const float* p) {
    const float4_* q4 = (const float4_*)p;
    float4_ lo = q4[0];
    float4_ hi = q4[1];
    short8 r;
    r[0] = (short)f2bf(lo[0]); r[1] = (short)f2bf(lo[1]);
    r[2] = (short)f2bf(lo[2]); r[3] = (short)f2bf(lo[3]);
    r[4] = (short)f2bf(hi[0]); r[5] = (short)f2bf(hi[1]);
    r[6] = (short)f2bf(hi[2]); r[7] = (short)f2bf(hi[3]);
    return r;
  }
  static __device__ __forceinline__ float ld1(const float* p) { return *p; }
};

template <typename T> __device__ __forceinline__ void storeOut(T* p, float v);
template <> __device__ __forceinline__ void storeOut<unsigned short>(unsigned short* p, float v) {
  *p = f2bf(v);
}
template <> __device__ __forceinline__ void storeOut<float>(float* p, float v) {
  *p = v;
}

// acc[NT] += act[16 x (KCH*32)] (LDS chunked) @ Wg[n0..][K]^T (global [N][K])
template <int KCH, int NT, typename T>
__device__ __forceinline__ void gemm_tiles(const unsigned short* act,
                                           const T* __restrict__ Wg,
                                           int K, int n0, int m16, int q,
                                           float4_* acc) {
  const T* wbase = Wg + (size_t)(n0 + m16) * K + q * 8;
#pragma unroll 4
  for (int kc = 0; kc < KCH; ++kc) {
    short8 a = *(const short8*)&act[kc * 640 + m16 * 40 + q * 8];
#pragma unroll
    for (int nt = 0; nt < NT; ++nt) {
      short8 b = Ld<T>::ld8(&wbase[(size_t)nt * 16 * K + kc * 32]);
      acc[nt] = __builtin_amdgcn_mfma_f32_16x16x32_bf16(a, b, acc[nt], 0, 0, 0);
    }
  }
}

template <typename T>
__device__ void run_all(const T* __restrict__ z0,
                        const T* __restrict__ w1, const T* __restrict__ b1,
                        const T* __restrict__ w2, const T* __restrict__ b2,
                        const T* __restrict__ w3, const T* __restrict__ b3,
                        const T* __restrict__ l2h_w, const T* __restrict__ l2h_b,
                        const T* __restrict__ h2o_w, const T* __restrict__ h2o_b,
                        T* __restrict__ out,
                        unsigned short* bufA, unsigned short* bufB) {
  const int tid = (int)threadIdx.x;
  const int wv = tid >> 6;
  const int ln = tid & 63;
  const int m16 = ln & 15;
  const int q = ln >> 4;
  const int row0 = (int)blockIdx.x * kRows;
  const int zc = wv * 16 + m16;
  const float hstep = 0.05f;  // DT / N_STEPS = 0.5 / 10

  // z slice in C/D fragment layout: reg r holds z[row0 + q*4 + r][zc].
  float zreg[4];
#pragma unroll
  for (int r = 0; r < 4; ++r)
    zreg[r] = Ld<T>::ld1(&z0[(size_t)(row0 + q * 4 + r) * kLatent + zc]);

  const float4_ zero4 = {0.0f, 0.0f, 0.0f, 0.0f};

  for (int t = 0; t < kT; ++t) {
    // publish current z (bf16) into bufA chunks 0..7
#pragma unroll
    for (int r = 0; r < 4; ++r)
      bufA[actIdx(q * 4 + r, zc)] = f2bf(zreg[r]);
    __syncthreads();

    // decode 1: hs = z @ l2h_w^T + l2h_b  (bufA -> bufB, linear)
    {
      float4_ acc[4] = {zero4, zero4, zero4, zero4};
      gemm_tiles<8, 4>(bufA, l2h_w, kLatent, wv * 64, m16, q, acc);
#pragma unroll
      for (int nt = 0; nt < 4; ++nt) {
        int n = wv * 64 + nt * 16 + m16;
        float bias = Ld<T>::ld1(&l2h_b[n]);
#pragma unroll
        for (int r = 0; r < 4; ++r)
          bufB[actIdx(q * 4 + r, n)] = f2bf(acc[nt][r] + bias);
      }
    }
    __syncthreads();

    // decode 2: xs = hs @ h2o_w^T + h2o_b  (bufB -> global)
    {
      float4_ acc[2] = {zero4, zero4};
      gemm_tiles<32, 2>(bufB, h2o_w, kHidden, wv * 32, m16, q, acc);
#pragma unroll
      for (int nt = 0; nt < 2; ++nt) {
        int n = wv * 32 + nt * 16 + m16;
        float bias = Ld<T>::ld1(&h2o_b[n]);
#pragma unroll
        for (int r = 0; r < 4; ++r) {
          size_t o = ((size_t)t * kB + row0 + q * 4 + r) * kOut + n;
          storeOut(&out[o], acc[nt][r] + bias);
        }
      }
    }
    __syncthreads();  // bufB reads done

    if (t == kT - 1) break;

    for (int s = 0; s < kSteps; ++s) {
      if (s > 0) {
#pragma unroll
        for (int r = 0; r < 4; ++r)
          bufA[actIdx(q * 4 + r, zc)] = f2bf(zreg[r]);
        __syncthreads();
      }
      // L1: h1 = ELU(z @ w1^T + b1)  (bufA -> bufB)
      {
        float4_ acc[4] = {zero4, zero4, zero4, zero4};
        gemm_tiles<8, 4>(bufA, w1, kLatent, wv * 64, m16, q, acc);
#pragma unroll
        for (int nt = 0; nt < 4; ++nt) {
          int n = wv * 64 + nt * 16 + m16;
          float bias = Ld<T>::ld1(&b1[n]);
#pragma unroll
          for (int r = 0; r < 4; ++r) {
            float v = acc[nt][r] + bias;
            v = v > 0.0f ? v : (expf(v) - 1.0f);
            bufB[actIdx(q * 4 + r, n)] = f2bf(v);
          }
        }
      }
      __syncthreads();

      // L2: h2 = ELU(h1 @ w2^T + b2)  (bufB -> bufA)
      {
        float4_ acc[4] = {zero4, zero4, zero4, zero4};
        gemm_tiles<32, 4>(bufB, w2, kHidden, wv * 64, m16, q, acc);
#pragma unroll
        for (int nt = 0; nt < 4; ++nt) {
          int n = wv * 64 + nt * 16 + m16;
          float bias = Ld<T>::ld1(&b2[n]);
#pragma unroll
          for (int r = 0; r < 4; ++r) {
            float v = acc[nt][r] + bias;
            v = v > 0.0f ? v : (expf(v) - 1.0f);
            bufA[actIdx(q * 4 + r, n)] = f2bf(v);
          }
        }
      }
      __syncthreads();

      // L3: dz = h2 @ w3^T + b3; z += h*dz  (bufA -> zreg)
      {
        float4_ acc1[1] = {zero4};
        gemm_tiles<32, 1>(bufA, w3, kHidden, wv * 16, m16, q, acc1);
        float bias = Ld<T>::ld1(&b3[zc]);
#pragma unroll
        for (int r = 0; r < 4; ++r)
          zreg[r] += hstep * (acc1[0][r] + bias);
      }
      __syncthreads();  // bufA reads done before next z publish
    }
  }
}

__global__ __launch_bounds__(1024) void node_fused(
    const void* z0, const void* tt,
    const void* w1, const void* b1, const void* w2, const void* b2,
    const void* w3, const void* b3, const void* l2h_w, const void* l2h_b,
    const void* h2o_w, const void* h2o_b, void* out) {
  __shared__ unsigned short bufA[32 * 640];  // 40 KB
  __shared__ unsigned short bufB[32 * 640];  // 40 KB

  // dtype discriminator: t[2] as fp32 word vs bf16 pair (2.0, 2.5)
  const unsigned disc = ((const unsigned*)tt)[2];
  if (disc == 0x3F800000u) {
    run_all<float>((const float*)z0,
                   (const float*)w1, (const float*)b1,
                   (const float*)w2, (const float*)b2,
                   (const float*)w3, (const float*)b3,
                   (const float*)l2h_w, (const float*)l2h_b,
                   (const float*)h2o_w, (const float*)h2o_b,
                   (float*)out, bufA, bufB);
  } else {
    run_all<unsigned short>((const unsigned short*)z0,
                            (const unsigned short*)w1, (const unsigned short*)b1,
                            (const unsigned short*)w2, (const unsigned short*)b2,
                            (const unsigned short*)w3, (const unsigned short*)b3,
                            (const unsigned short*)l2h_w, (const unsigned short*)l2h_b,
                            (const unsigned short*)h2o_w, (const unsigned short*)h2o_b,
                            (unsigned short*)out, bufA, bufB);
  }
}

extern "C" void kernel_launch(void* const* d_in, const int* in_sizes, int n_in,
                              void* d_out, int out_size, void* d_ws, size_t ws_size,
                              hipStream_t stream) {
  node_fused<<<dim3(kB / kRows), dim3(1024), 0, stream>>>(
      d_in[0], d_in[1], d_in[2], d_in[3], d_in[4], d_in[5], d_in[6], d_in[7],
      d_in[8], d_in[9], d_in[10], d_in[11], d_out);
}